// Round 4
// baseline (315.107 us; speedup 1.0000x reference)
//
#include <hip/hip_runtime.h>
#include <hip/hip_bf16.h>

// Per (b,c) slice: S = (Q K^T)*di ; A = softmax_rows(S) ; out[i,j] = sum_k A[j,k] V[i,k]
// j-tile 64 (4 blocks/slice, XCD-grouped), 8 waves, fp16 MFMA (32x32x16).
// No K/V LDS staging: operands load straight from global (L2-served).
// Only LDS: attn weights (fp16, swizzled) + softmax (m,sum) partials.
// Barriers per block: 2.

typedef __attribute__((ext_vector_type(8))) _Float16 f16x8;
typedef __attribute__((ext_vector_type(4))) float f32x4;
typedef __attribute__((ext_vector_type(16))) float f32x16;

__device__ __forceinline__ f32x16 mfma32h(f16x8 a, f16x8 b, f32x16 c) {
  return __builtin_amdgcn_mfma_f32_32x32x16_f16(a, b, c, 0, 0, 0);
}
__device__ __forceinline__ f16x8 cvt8(f32x4 a, f32x4 b) {
  f16x8 r;
  r[0] = (_Float16)a[0]; r[1] = (_Float16)a[1];
  r[2] = (_Float16)a[2]; r[3] = (_Float16)a[3];
  r[4] = (_Float16)b[0]; r[5] = (_Float16)b[1];
  r[6] = (_Float16)b[2]; r[7] = (_Float16)b[3];
  return r;
}
// [64][256] fp16 tile, 512B row stride: XOR 4 row bits into the 16B-slot index
__device__ __forceinline__ int swzA(int row, int byteCol) {
  return row * 512 + (byteCol ^ ((row & 15) << 4));
}

__global__ __launch_bounds__(512, 4) void attn_fused4(
    const float* __restrict__ Q, const float* __restrict__ K,
    const float* __restrict__ V, const float* __restrict__ di,
    float* __restrict__ out) {
  __shared__ short Abuf[64 * 256];  // fp16 weights, swizzled (32KB)
  __shared__ float pmps[64 * 8];    // per row: 4 kt x (max, sum) (2KB)

  const int t = threadIdx.x;
  const int lane = t & 63;
  const int wv = t >> 6;  // 0..7
  const int l31 = lane & 31;
  const int h5 = lane >> 5;  // 0..1

  // 4 sibling blocks of one slice share bid%8 -> same XCD L2
  const int bid = blockIdx.x;
  const int bc = (bid >> 5) * 8 + (bid & 7);  // slice 0..511
  const int j0 = ((bid >> 3) & 3) * 64;       // j-tile origin

  const float dival = di[0];
  const size_t base = (size_t)bc << 16;
  const float* Qs = Q + base;
  const float* Ks = K + base;
  const float* Vs = V + base;
  float* Os = out + base;

  const int jt = wv & 1;   // j sub-tile (32 rows)
  const int kt = wv >> 1;  // k range (64 cols)

  // ---- Q fragments: rows j0+32jt+l31, w-elems 16s+8h5.. (A-op layout) ----
  f16x8 q[16];
  {
    const float* qp = Qs + (size_t)(j0 + 32 * jt + l31) * 256 + 8 * h5;
#pragma unroll
    for (int s = 0; s < 16; ++s)
      q[s] =
          cvt8(*(const f32x4*)(qp + 16 * s), *(const f32x4*)(qp + 16 * s + 4));
  }

  // ---- mm1: S[32j x 64k] = Q K^T, direct global K loads, no barriers ----
  f32x16 s0 = {}, s1 = {};  // k cols 64kt+l31 and 64kt+32+l31
  {
    const float* kp = Ks + (size_t)(64 * kt + l31) * 256 + 8 * h5;
#pragma unroll
    for (int s = 0; s < 16; ++s) {
      f16x8 k0 = cvt8(*(const f32x4*)(kp + 16 * s),
                      *(const f32x4*)(kp + 16 * s + 4));
      f16x8 k1 = cvt8(*(const f32x4*)(kp + 8192 + 16 * s),
                      *(const f32x4*)(kp + 8192 + 16 * s + 4));
      s0 = mfma32h(q[s], k0, s0);
      s1 = mfma32h(q[s], k1, s1);
    }
  }

  // ---- softmax: wave-local (over 64 cols) then cross-wave combine ----
  // lane holds S[row = 32jt + (r&3)+8(r>>2)+4h5][cols above]
  float mloc[16];
#pragma unroll
  for (int r = 0; r < 16; ++r) {
    float x0 = s0[r] * dival, x1 = s1[r] * dival;
    float m = fmaxf(x0, x1);
#pragma unroll
    for (int o = 1; o <= 16; o <<= 1) m = fmaxf(m, __shfl_xor(m, o));
    float e0 = __expf(x0 - m), e1 = __expf(x1 - m);
    float sm = e0 + e1;
#pragma unroll
    for (int o = 1; o <= 16; o <<= 1) sm += __shfl_xor(sm, o);
    s0[r] = e0;
    s1[r] = e1;
    mloc[r] = m;
    if (l31 == 0) {
      const int row = 32 * jt + (r & 3) + 8 * (r >> 2) + 4 * h5;
      pmps[row * 8 + kt * 2] = m;
      pmps[row * 8 + kt * 2 + 1] = sm;
    }
  }
  __syncthreads();  // partials visible

#pragma unroll
  for (int r = 0; r < 16; ++r) {
    const int row = 32 * jt + (r & 3) + 8 * (r >> 2) + 4 * h5;
    f32x4 p0 = *(const f32x4*)&pmps[row * 8];
    f32x4 p1 = *(const f32x4*)&pmps[row * 8 + 4];
    float mg = fmaxf(fmaxf(p0[0], p0[2]), fmaxf(p1[0], p1[2]));
    float S = p0[1] * __expf(p0[0] - mg) + p0[3] * __expf(p0[2] - mg) +
              p1[1] * __expf(p1[0] - mg) + p1[3] * __expf(p1[2] - mg);
    const float al = __expf(mloc[r] - mg) / S;
    const _Float16 w0 = (_Float16)(s0[r] * al);
    const _Float16 w1 = (_Float16)(s1[r] * al);
    *(_Float16*)((char*)Abuf + swzA(row, 2 * (64 * kt + l31))) = w0;
    *(_Float16*)((char*)Abuf + swzA(row, 2 * (64 * kt + 32 + l31))) = w1;
  }
  __syncthreads();  // A visible

  // ---- mm2: out[32i x 64j] = sum_k V[i,k] A[j,k]; V direct from global ----
  f32x16 o0 = {}, o1 = {};
  {
    const float* vp = Vs + (size_t)(32 * wv + l31) * 256 + 8 * h5;
#pragma unroll
    for (int ks = 0; ks < 16; ++ks) {
      f16x8 va = cvt8(*(const f32x4*)(vp + 16 * ks),
                      *(const f32x4*)(vp + 16 * ks + 4));
      const int colB = 32 * ks + 16 * h5;  // byteCol = 2*(16ks + 8h5)
      f16x8 ab0 = *(const f16x8*)((const char*)Abuf + swzA(l31, colB));
      f16x8 ab1 = *(const f16x8*)((const char*)Abuf + swzA(32 + l31, colB));
      o0 = mfma32h(va, ab0, o0);
      o1 = mfma32h(va, ab1, o1);
    }
  }

  // ---- stores: D layout col=l31(+32), row=(r&3)+8(r>>2)+4h5 ----
#pragma unroll
  for (int r = 0; r < 16; ++r) {
    const int rw = 32 * wv + (r & 3) + 8 * (r >> 2) + 4 * h5;
    Os[(size_t)rw * 256 + j0 + l31] = o0[r];
    Os[(size_t)rw * 256 + j0 + 32 + l31] = o1[r];
  }
}

extern "C" void kernel_launch(void* const* d_in, const int* in_sizes, int n_in,
                              void* d_out, int out_size, void* d_ws,
                              size_t ws_size, hipStream_t stream) {
  const float* Q = (const float*)d_in[0];
  const float* K = (const float*)d_in[1];
  const float* V = (const float*)d_in[2];
  const float* di = (const float*)d_in[3];
  float* out = (float*)d_out;
  const int BC = in_sizes[0] / (256 * 256);  // 512 slices
  hipLaunchKernelGGL(attn_fused4, dim3(BC * 4), dim3(512), 0, stream, Q, K, V,
                     di, out);
}

// Round 5
// 166.816 us; speedup vs baseline: 1.8890x; 1.8890x over previous
//
#include <hip/hip_runtime.h>
#include <hip/hip_bf16.h>

// Per (b,c) slice: S = (Q K^T)*di ; A = softmax_rows(S) ; out[i,j] = sum_k A[j,k] V[i,k]
// j-tile 64 (4 blocks/slice, XCD-grouped), 8 waves, fp16 MFMA.
// mm1: 16x16x32 f16, K staged fp16 double-buffered; S in regs.
// softmax: in-register + cross-wave (m,s) combine via 1KB LDS partials.
// mm2: 32x32x16 f16, V staged [256 i][64 k] fp16; P (fp16) in 32KB LDS.
// LDS ~65KB -> 2 blocks/CU.

typedef __attribute__((ext_vector_type(8))) _Float16 f16x8;
typedef __attribute__((ext_vector_type(4))) float f32x4;
typedef __attribute__((ext_vector_type(16))) float f32x16;

__device__ __forceinline__ f32x4 mfma16h(f16x8 a, f16x8 b, f32x4 c) {
  return __builtin_amdgcn_mfma_f32_16x16x32_f16(a, b, c, 0, 0, 0);
}
__device__ __forceinline__ f32x16 mfma32h(f16x8 a, f16x8 b, f32x16 c) {
  return __builtin_amdgcn_mfma_f32_32x32x16_f16(a, b, c, 0, 0, 0);
}
__device__ __forceinline__ f16x8 cvt8(f32x4 a, f32x4 b) {
  f16x8 r;
  r[0] = (_Float16)a[0]; r[1] = (_Float16)a[1];
  r[2] = (_Float16)a[2]; r[3] = (_Float16)a[3];
  r[4] = (_Float16)b[0]; r[5] = (_Float16)b[1];
  r[6] = (_Float16)b[2]; r[7] = (_Float16)b[3];
  return r;
}
// 512B-row-stride fp16 tiles ([*][256]): XOR 4 row bits into the 16B-slot idx
__device__ __forceinline__ int swzA(int row, int byteCol) {
  return row * 512 + (byteCol ^ ((row & 15) << 4));
}
// 128B-row-stride fp16 tile ([256][64]): 3 row bits
__device__ __forceinline__ int swzV(int row, int byteCol) {
  return row * 128 + (byteCol ^ ((row & 7) << 4));
}

__global__ __launch_bounds__(512, 4) void attn_fused5(
    const float* __restrict__ Q, const float* __restrict__ K,
    const float* __restrict__ V, const float* __restrict__ di,
    float* __restrict__ out) {
  __shared__ short Khi[2][32 * 256];  // 2x16KB fp16 K chunks; alias Vlds mm2
  __shared__ short Abuf[64 * 256];    // 32KB fp16 attn weights, swizzled
  __shared__ float pmps[64 * 4];      // per row: kt x (max, sum)
  short* Vlds = &Khi[0][0];           // [256 i][64 k] fp16 = 32KB (alias)

  const int t = threadIdx.x;
  const int lane = t & 63;
  const int wv = t >> 6;     // 0..7
  const int l15 = lane & 15;
  const int l4 = (lane >> 4) & 3;
  const int l31 = lane & 31;
  const int h5 = lane >> 5;  // 0..1

  // 4 sibling blocks of one slice share bid%8 -> same XCD L2
  const int bid = blockIdx.x;
  const int bc = (bid >> 5) * 8 + (bid & 7);  // slice
  const int j0 = ((bid >> 3) & 3) * 64;       // j-tile origin

  const float dival = di[0];
  const size_t base = (size_t)bc << 16;
  const float* Qs = Q + base;
  const float* Ks = K + base;
  const float* Vs = V + base;
  float* Os = out + base;

  const int jt = wv >> 1;  // mm1 j-group (16 rows)
  const int kt = wv & 1;   // mm1 k-half of each chunk

  // K staging coords: thread loads 16 consecutive floats of a 32x256 chunk
  const int sr = t >> 4;
  const int sc = (t & 15) << 4;

  f32x4 c0, c1, c2, c3;
  {  // K chunk 0 loads in flight
    const float* p = Ks + sr * 256 + sc;
    c0 = *(const f32x4*)p;
    c1 = *(const f32x4*)(p + 4);
    c2 = *(const f32x4*)(p + 8);
    c3 = *(const f32x4*)(p + 12);
  }
  f16x8 qh[8];  // wave's 16 Q rows (A-op layout), fp16
  {
    const float* qrow = Qs + (size_t)(j0 + 16 * jt + l15) * 256 + 8 * l4;
#pragma unroll
    for (int s = 0; s < 8; ++s)
      qh[s] =
          cvt8(*(const f32x4*)(qrow + 32 * s), *(const f32x4*)(qrow + 32 * s + 4));
  }

  f32x4 acc[8];  // S rows j = 16jt+4l4+r ; cols k = 32ch + 16kt + l15
#pragma unroll
  for (int i = 0; i < 8; ++i) acc[i] = (f32x4){0.f, 0.f, 0.f, 0.f};

  // ---- matmul 1 ----
#pragma unroll
  for (int ch = 0; ch < 8; ++ch) {
    short* hi = Khi[ch & 1];
    {  // fp32 -> fp16, write LDS (swizzled)
      f16x8 h0 = cvt8(c0, c1), h1 = cvt8(c2, c3);
      *(f16x8*)((char*)hi + swzA(sr, sc * 2)) = h0;
      *(f16x8*)((char*)hi + swzA(sr, sc * 2 + 16)) = h1;
    }
    __syncthreads();
    if (ch < 7) {  // prefetch next K chunk; flies under MFMA
      const float* p = Ks + (ch + 1) * 32 * 256 + sr * 256 + sc;
      c0 = *(const f32x4*)p;
      c1 = *(const f32x4*)(p + 4);
      c2 = *(const f32x4*)(p + 8);
      c3 = *(const f32x4*)(p + 12);
    }
    __builtin_amdgcn_s_setprio(1);
    const int kr = 16 * kt + l15;
    f32x4 a = acc[ch];
#pragma unroll
    for (int s = 0; s < 8; ++s) {
      f16x8 bh = *(const f16x8*)((const char*)hi + swzA(kr, 64 * s + 16 * l4));
      a = mfma16h(qh[s], bh, a);
    }
    acc[ch] = a;
    __builtin_amdgcn_s_setprio(0);
  }

  // ---- V k-chunk 0 prefetch (flies under softmax): [256 i][64 k] ----
  const int vr = t >> 1;
  const int vh = (t & 1) * 32;
  f32x4 vc0, vc1, vc2, vc3, vc4, vc5, vc6, vc7;
  {
    const float* p = Vs + (size_t)vr * 256 + vh;
    vc0 = *(const f32x4*)p;
    vc1 = *(const f32x4*)(p + 4);
    vc2 = *(const f32x4*)(p + 8);
    vc3 = *(const f32x4*)(p + 12);
    vc4 = *(const f32x4*)(p + 16);
    vc5 = *(const f32x4*)(p + 20);
    vc6 = *(const f32x4*)(p + 24);
    vc7 = *(const f32x4*)(p + 28);
  }

  // ---- softmax: wave-half local (128 k) then cross-wave combine ----
  float mx[4];
#pragma unroll
  for (int r = 0; r < 4; ++r) mx[r] = -1e30f;
#pragma unroll
  for (int ch = 0; ch < 8; ++ch)
#pragma unroll
    for (int r = 0; r < 4; ++r) {
      acc[ch][r] *= dival;
      mx[r] = fmaxf(mx[r], acc[ch][r]);
    }
#pragma unroll
  for (int o = 1; o <= 8; o <<= 1)
#pragma unroll
    for (int r = 0; r < 4; ++r) mx[r] = fmaxf(mx[r], __shfl_xor(mx[r], o));
  float sm[4] = {0.f, 0.f, 0.f, 0.f};
#pragma unroll
  for (int ch = 0; ch < 8; ++ch)
#pragma unroll
    for (int r = 0; r < 4; ++r) {
      acc[ch][r] = __expf(acc[ch][r] - mx[r]);
      sm[r] += acc[ch][r];
    }
#pragma unroll
  for (int o = 1; o <= 8; o <<= 1)
#pragma unroll
    for (int r = 0; r < 4; ++r) sm[r] += __shfl_xor(sm[r], o);
  if (l15 == 0) {
#pragma unroll
    for (int r = 0; r < 4; ++r) {
      const int row = 16 * jt + 4 * l4 + r;
      pmps[row * 4 + 2 * kt] = mx[r];
      pmps[row * 4 + 2 * kt + 1] = sm[r];
    }
  }
  __syncthreads();  // partials visible
#pragma unroll
  for (int r = 0; r < 4; ++r) {
    const int row = 16 * jt + 4 * l4 + r;
    f32x4 p = *(const f32x4*)&pmps[row * 4];
    const float mg = fmaxf(p[0], p[2]);
    const float Sg = p[1] * __expf(p[0] - mg) + p[3] * __expf(p[2] - mg);
    const float al = __expf(mx[r] - mg) / Sg;
#pragma unroll
    for (int ch = 0; ch < 8; ++ch) {
      const int col = 32 * ch + 16 * kt + l15;
      *(_Float16*)((char*)Abuf + swzA(row, 2 * col)) =
          (_Float16)(acc[ch][r] * al);
    }
  }
  __syncthreads();  // A visible; all K-LDS reads done (Vlds alias safe)

  // ---- matmul 2: 32x32x16, wave = 64i x 32j ----
  const int it = wv >> 1;   // i-base/64
  const int jt2 = wv & 1;   // j-group of 32
  f32x16 o0 = {}, o1 = {};
#pragma unroll
  for (int kc = 0; kc < 4; ++kc) {
    {  // V fp32 -> fp16, write Vlds[vr][vh..vh+31]
      *(f16x8*)((char*)Vlds + swzV(vr, vh * 2)) = cvt8(vc0, vc1);
      *(f16x8*)((char*)Vlds + swzV(vr, vh * 2 + 16)) = cvt8(vc2, vc3);
      *(f16x8*)((char*)Vlds + swzV(vr, vh * 2 + 32)) = cvt8(vc4, vc5);
      *(f16x8*)((char*)Vlds + swzV(vr, vh * 2 + 48)) = cvt8(vc6, vc7);
    }
    __syncthreads();  // V chunk visible
    if (kc < 3) {     // prefetch next V k-chunk; flies under MFMA
      const float* p = Vs + (size_t)vr * 256 + (kc + 1) * 64 + vh;
      vc0 = *(const f32x4*)p;
      vc1 = *(const f32x4*)(p + 4);
      vc2 = *(const f32x4*)(p + 8);
      vc3 = *(const f32x4*)(p + 12);
      vc4 = *(const f32x4*)(p + 16);
      vc5 = *(const f32x4*)(p + 20);
      vc6 = *(const f32x4*)(p + 24);
      vc7 = *(const f32x4*)(p + 28);
    }
    __builtin_amdgcn_s_setprio(1);
#pragma unroll
    for (int ks = 0; ks < 4; ++ks) {
      const int colV = 32 * ks + 16 * h5;
      f16x8 va0 =
          *(const f16x8*)((const char*)Vlds + swzV(64 * it + l31, colV));
      f16x8 va1 =
          *(const f16x8*)((const char*)Vlds + swzV(64 * it + 32 + l31, colV));
      const int colA = 32 * (4 * kc + ks) + 16 * h5;
      f16x8 pb =
          *(const f16x8*)((const char*)Abuf + swzA(32 * jt2 + l31, colA));
      o0 = mfma32h(va0, pb, o0);
      o1 = mfma32h(va1, pb, o1);
    }
    __builtin_amdgcn_s_setprio(0);
    __syncthreads();  // reads done before next chunk overwrite
  }

  // ---- stores: D col=l31, row=(r&3)+8(r>>2)+4h5 ----
#pragma unroll
  for (int r = 0; r < 16; ++r) {
    const int rw = (r & 3) + 8 * (r >> 2) + 4 * h5;
    const int col = j0 + 32 * jt2 + l31;
    Os[(size_t)(64 * it + rw) * 256 + col] = o0[r];
    Os[(size_t)(64 * it + 32 + rw) * 256 + col] = o1[r];
  }
}

extern "C" void kernel_launch(void* const* d_in, const int* in_sizes, int n_in,
                              void* d_out, int out_size, void* d_ws,
                              size_t ws_size, hipStream_t stream) {
  const float* Q = (const float*)d_in[0];
  const float* K = (const float*)d_in[1];
  const float* V = (const float*)d_in[2];
  const float* di = (const float*)d_in[3];
  float* out = (float*)d_out;
  const int BC = in_sizes[0] / (256 * 256);  // 512 slices
  hipLaunchKernelGGL(attn_fused5, dim3(BC * 4), dim3(512), 0, stream, Q, K, V,
                     di, out);
}

// Round 6
// 130.066 us; speedup vs baseline: 2.4227x; 1.2825x over previous
//
#include <hip/hip_runtime.h>
#include <hip/hip_bf16.h>

// Per (b,c) slice: S = (Q K^T)*di ; A = softmax_rows(S) ; out[i,j] = sum_k A[j,k] V[i,k]
// j-tile 128 (2 blocks/slice, XCD-paired), 8 waves, all fp16 MFMA.
// mm1: 16x16x32, K fp16 2-deep-prefetch dbuf; full softmax in-register per wave.
// mm2: 32x32x16, A-frags preloaded to regs (pb[16]); V 64-row fp16 chunks.
// Raw s_barrier + lgkmcnt only (NO __syncthreads -> no vmcnt(0) drain;
// global prefetches stay in flight across barriers).

typedef __attribute__((ext_vector_type(8))) _Float16 f16x8;
typedef __attribute__((ext_vector_type(4))) float f32x4;
typedef __attribute__((ext_vector_type(16))) float f32x16;

#define BARRIER() asm volatile("s_waitcnt lgkmcnt(0)\n\ts_barrier" ::: "memory")

__device__ __forceinline__ f32x4 mfma16h(f16x8 a, f16x8 b, f32x4 c) {
  return __builtin_amdgcn_mfma_f32_16x16x32_f16(a, b, c, 0, 0, 0);
}
__device__ __forceinline__ f32x16 mfma32h(f16x8 a, f16x8 b, f32x16 c) {
  return __builtin_amdgcn_mfma_f32_32x32x16_f16(a, b, c, 0, 0, 0);
}
__device__ __forceinline__ f16x8 cvt8(f32x4 a, f32x4 b) {
  f16x8 r;
  r[0] = (_Float16)a[0]; r[1] = (_Float16)a[1];
  r[2] = (_Float16)a[2]; r[3] = (_Float16)a[3];
  r[4] = (_Float16)b[0]; r[5] = (_Float16)b[1];
  r[6] = (_Float16)b[2]; r[7] = (_Float16)b[3];
  return r;
}
// 512B-row-stride fp16 tiles: XOR 4 row bits into the 16B-slot index
__device__ __forceinline__ int swz(int row, int byteCol) {
  return row * 512 + (byteCol ^ ((row & 15) << 4));
}

__global__ __launch_bounds__(512, 2) void attn_fused6(
    const float* __restrict__ Q, const float* __restrict__ K,
    const float* __restrict__ V, const float* __restrict__ di,
    float* __restrict__ out) {
  __shared__ short Kbuf[2][32 * 256];  // fp16 K chunks, 32KB; aliased by Vlds
  __shared__ short Abuf[128 * 256];    // fp16 attn weights, 64KB, swizzled
  short* Vlds = &Kbuf[0][0];           // [64 i][256 k] fp16 = 32KB (alias)

  const int t = threadIdx.x;
  const int lane = t & 63;
  const int wv = t >> 6;     // 0..7
  const int l15 = lane & 15;
  const int l4 = (lane >> 4) & 3;
  const int l31 = lane & 31;
  const int h5 = lane >> 5;  // 0..1

  // 2 sibling blocks of one slice share bid%8 -> same XCD L2 (round-robin HW)
  const int bid = blockIdx.x;
  const int bc = (bid >> 4) * 8 + (bid & 7);  // slice 0..511
  const int j0 = ((bid >> 3) & 1) << 7;       // 0 or 128

  const float dival = di[0];
  const size_t base = (size_t)bc << 16;
  const float* Qs = Q + base;
  const float* Ks = K + base;
  const float* Vs = V + base;
  float* Os = out + base;

  // K staging coords: thread loads 16 consecutive floats of a 32x256 chunk
  const int sr = t >> 4;
  const int sc = (t & 15) << 4;

  f32x4 ka0, ka1, ka2, ka3, kb0, kb1, kb2, kb3;  // 2-deep K prefetch
  {  // K chunks 0 and 1 in flight
    const float* p = Ks + sr * 256 + sc;
    ka0 = *(const f32x4*)p;
    ka1 = *(const f32x4*)(p + 4);
    ka2 = *(const f32x4*)(p + 8);
    ka3 = *(const f32x4*)(p + 12);
    const float* q = p + 8192;
    kb0 = *(const f32x4*)q;
    kb1 = *(const f32x4*)(q + 4);
    kb2 = *(const f32x4*)(q + 8);
    kb3 = *(const f32x4*)(q + 12);
  }
  f16x8 qh[8];  // wave's 16 Q rows (A-op layout)
  {
    const float* qrow = Qs + (size_t)(j0 + wv * 16 + l15) * 256 + 8 * l4;
#pragma unroll
    for (int s = 0; s < 8; ++s)
      qh[s] = cvt8(*(const f32x4*)(qrow + 32 * s),
                   *(const f32x4*)(qrow + 32 * s + 4));
  }

  f32x4 acc[16];  // S rows j=wv*16+4*l4+r ; cols k = 32*idx/2.. (16 frags)
#pragma unroll
  for (int i = 0; i < 16; ++i) acc[i] = (f32x4){0.f, 0.f, 0.f, 0.f};

  // ---- matmul 1: per chunk: write LDS, issue ch+2, barrier, MFMA ----
#pragma unroll
  for (int ch = 0; ch < 8; ++ch) {
    short* kb = Kbuf[ch & 1];
    if ((ch & 1) == 0) {
      *(f16x8*)((char*)kb + swz(sr, sc * 2)) = cvt8(ka0, ka1);
      *(f16x8*)((char*)kb + swz(sr, sc * 2 + 16)) = cvt8(ka2, ka3);
      if (ch < 6) {
        const float* p = Ks + (ch + 2) * 8192 + sr * 256 + sc;
        ka0 = *(const f32x4*)p;
        ka1 = *(const f32x4*)(p + 4);
        ka2 = *(const f32x4*)(p + 8);
        ka3 = *(const f32x4*)(p + 12);
      }
    } else {
      *(f16x8*)((char*)kb + swz(sr, sc * 2)) = cvt8(kb0, kb1);
      *(f16x8*)((char*)kb + swz(sr, sc * 2 + 16)) = cvt8(kb2, kb3);
      if (ch < 6) {
        const float* p = Ks + (ch + 2) * 8192 + sr * 256 + sc;
        kb0 = *(const f32x4*)p;
        kb1 = *(const f32x4*)(p + 4);
        kb2 = *(const f32x4*)(p + 8);
        kb3 = *(const f32x4*)(p + 12);
      }
    }
    BARRIER();  // LDS writes visible; prior-phase reads done; vmem in flight
    __builtin_amdgcn_s_setprio(1);
#pragma unroll
    for (int kf = 0; kf < 2; ++kf) {
      const int kr = kf * 16 + l15;
      f32x4 a = acc[2 * ch + kf];
#pragma unroll
      for (int s = 0; s < 8; ++s) {
        f16x8 bh = *(const f16x8*)((const char*)kb + swz(kr, 64 * s + 16 * l4));
        a = mfma16h(qh[s], bh, a);
      }
      acc[2 * ch + kf] = a;
    }
    __builtin_amdgcn_s_setprio(0);
  }

  // ---- V chunk 0 prefetch (flies under softmax): rows 0..63 ----
  const int vr = t >> 3;         // local i-row 0..63
  const int vc = (t & 7) << 5;   // float col, 32 per thread
  f32x4 va[8], vb[8];
  {
    const float* p = Vs + (size_t)vr * 256 + vc;
#pragma unroll
    for (int e = 0; e < 8; ++e) va[e] = *(const f32x4*)(p + 4 * e);
  }

  // ---- softmax: full k per wave, in-register ----
  float mx[4] = {-1e30f, -1e30f, -1e30f, -1e30f};
#pragma unroll
  for (int idx = 0; idx < 16; ++idx)
#pragma unroll
    for (int r = 0; r < 4; ++r) {
      acc[idx][r] *= dival;
      mx[r] = fmaxf(mx[r], acc[idx][r]);
    }
#pragma unroll
  for (int o = 1; o <= 8; o <<= 1)
#pragma unroll
    for (int r = 0; r < 4; ++r) mx[r] = fmaxf(mx[r], __shfl_xor(mx[r], o));
  float sm[4] = {0.f, 0.f, 0.f, 0.f};
#pragma unroll
  for (int idx = 0; idx < 16; ++idx)
#pragma unroll
    for (int r = 0; r < 4; ++r) {
      acc[idx][r] = __expf(acc[idx][r] - mx[r]);
      sm[r] += acc[idx][r];
    }
#pragma unroll
  for (int o = 1; o <= 8; o <<= 1)
#pragma unroll
    for (int r = 0; r < 4; ++r) sm[r] += __shfl_xor(sm[r], o);
#pragma unroll
  for (int r = 0; r < 4; ++r) sm[r] = 1.0f / sm[r];
  // A (fp16) -> Abuf, swizzled: row = local j, col = k
#pragma unroll
  for (int idx = 0; idx < 16; ++idx)
#pragma unroll
    for (int r = 0; r < 4; ++r) {
      const int row = wv * 16 + 4 * l4 + r;
      *(_Float16*)((char*)Abuf + swz(row, 2 * (idx * 16 + l15))) =
          (_Float16)(acc[idx][r] * sm[r]);
    }
  BARRIER();  // A visible; all mm1 K-LDS reads done (Vlds alias safe)

  // ---- preload A-fragments: pb[kk] = A[jg..jg+31][16kk + 8h5 ..] ----
  const int ih = wv >> 2;        // i-half of 64-row V chunk
  const int jg = (wv & 3) * 32;  // j-group
  f16x8 pb[16];
#pragma unroll
  for (int kk = 0; kk < 16; ++kk)
    pb[kk] =
        *(const f16x8*)((const char*)Abuf + swz(jg + l31, 32 * kk + 16 * h5));

  // ---- matmul 2: 4 chunks of 64 i-rows; wave tile 32i x 32j ----
#pragma unroll
  for (int ci = 0; ci < 4; ++ci) {
    if ((ci & 1) == 0) {
#pragma unroll
      for (int e = 0; e < 4; ++e) {
        *(f16x8*)((char*)Vlds + swz(vr, vc * 2 + 16 * e)) =
            cvt8(va[2 * e], va[2 * e + 1]);
      }
      if (ci < 3) {  // issue next V chunk into the other buffer
        const float* p = Vs + (size_t)((ci + 1) * 64 + vr) * 256 + vc;
#pragma unroll
        for (int e = 0; e < 8; ++e) vb[e] = *(const f32x4*)(p + 4 * e);
      }
    } else {
#pragma unroll
      for (int e = 0; e < 4; ++e) {
        *(f16x8*)((char*)Vlds + swz(vr, vc * 2 + 16 * e)) =
            cvt8(vb[2 * e], vb[2 * e + 1]);
      }
      if (ci < 3) {
        const float* p = Vs + (size_t)((ci + 1) * 64 + vr) * 256 + vc;
#pragma unroll
        for (int e = 0; e < 8; ++e) va[e] = *(const f32x4*)(p + 4 * e);
      }
    }
    BARRIER();  // V chunk visible
    __builtin_amdgcn_s_setprio(1);
    f32x16 o = {};
#pragma unroll
    for (int kk = 0; kk < 16; ++kk) {
      f16x8 vfrag = *(const f16x8*)((const char*)Vlds +
                                    swz(ih * 32 + l31, 32 * kk + 16 * h5));
      o = mfma32h(vfrag, pb[kk], o);
    }
    __builtin_amdgcn_s_setprio(0);
    // store 32x32 tile: D col=l31, row=(reg&3)+8*(reg>>2)+4*h5
    const int rbase = ci * 64 + ih * 32 + 4 * h5;
    const int col = j0 + jg + l31;
#pragma unroll
    for (int reg = 0; reg < 16; ++reg) {
      const int rw = (reg & 3) + 8 * (reg >> 2);
      Os[(size_t)(rbase + rw) * 256 + col] = o[reg];
    }
    BARRIER();  // reads done before next chunk's write
  }
}

extern "C" void kernel_launch(void* const* d_in, const int* in_sizes, int n_in,
                              void* d_out, int out_size, void* d_ws,
                              size_t ws_size, hipStream_t stream) {
  const float* Q = (const float*)d_in[0];
  const float* K = (const float*)d_in[1];
  const float* V = (const float*)d_in[2];
  const float* di = (const float*)d_in[3];
  float* out = (float*)d_out;
  const int BC = in_sizes[0] / (256 * 256);  // 512 slices
  hipLaunchKernelGGL(attn_fused6, dim3(BC * 2), dim3(512), 0, stream, Q, K, V,
                     di, out);
}